// Round 3
// baseline (443.052 us; speedup 1.0000x reference)
//
#include <hip/hip_runtime.h>

#define NBINS 10
#define BLOCK 256
#define NW (BLOCK / 64)

// Per element:
//   u   = (1-2t)*x          (t in {0,1} exactly -> g = sigmoid(u))
//   e   = exp(-|u|)
//   g   = u>=0 ? 1/(1+e) : e/(1+e)     == |sigmoid(x) - t|
//   bce = max(u,0) + log(1+e)          == stable BCE-with-logits
// Bin masks reproduce reference semantics exactly:
//   count bin k:  g >= E[k] && g <= E[k+1]   (boundaries double-counted)
//   assign bin k: g >= E[k] && g <  E[k+1]   (boundary goes to upper bin,
//                                             = torch/jax later-overwrite)
__device__ __forceinline__ void process_elem(float x, float tv,
                                             unsigned int cnt[NBINS],
                                             float fs[NBINS]) {
    const float E[NBINS + 1] = {0.0f, 0.1f, 0.2f, 0.3f, 0.4f, 0.5f,
                                0.6f, 0.7f, 0.8f, 0.9f, 1.000001f};
    float u    = x * (1.0f - 2.0f * tv);
    float au   = fabsf(u);
    float e    = __expf(-au);                      // v_exp path
    float ope  = 1.0f + e;
    float r    = __builtin_amdgcn_rcpf(ope);       // v_rcp_f32, ~1 ulp
    float g    = (u >= 0.0f) ? r : e * r;          // sigmoid(u)
    float bce  = fmaxf(u, 0.0f) + __logf(ope);     // softplus(u)

    bool ge[NBINS + 1];
    bool gt[NBINS + 1];
    ge[0] = true;  gt[0] = true;                   // g >= 0 always
    ge[NBINS] = false; gt[NBINS] = false;          // g <= 1 < 1.000001 always
#pragma unroll
    for (int k = 1; k < NBINS; ++k) {
        ge[k] = (g >= E[k]);
        gt[k] = (g >  E[k]);
    }
#pragma unroll
    for (int k = 0; k < NBINS; ++k) {
        cnt[k] += (ge[k] && !gt[k + 1]) ? 1u : 0u;   // inclusive count
        fs[k]  += (ge[k] && !ge[k + 1]) ? bce : 0.0f; // assignment sum
    }
}

// direct==0: write per-block partials to ws.  direct==1 (single block,
// ws-less fallback): compute the final loss and write out[0].
__global__ __launch_bounds__(BLOCK) void ghmc_main(
    const float* __restrict__ pred, const float* __restrict__ target,
    unsigned int* __restrict__ ws_cnt, float* __restrict__ ws_sum,
    long long nvec, long long ntot, int direct, float* __restrict__ out) {
    unsigned int cnt[NBINS];
    float fs[NBINS];
#pragma unroll
    for (int k = 0; k < NBINS; ++k) { cnt[k] = 0u; fs[k] = 0.0f; }

    const long long stride = (long long)gridDim.x * BLOCK;
    const long long tid0   = (long long)blockIdx.x * BLOCK + threadIdx.x;

    const float4* p4 = (const float4*)pred;
    const float4* t4 = (const float4*)target;
    for (long long i = tid0; i < nvec; i += stride) {
        float4 p = p4[i];
        float4 t = t4[i];
        process_elem(p.x, t.x, cnt, fs);
        process_elem(p.y, t.y, cnt, fs);
        process_elem(p.z, t.z, cnt, fs);
        process_elem(p.w, t.w, cnt, fs);
    }
    // scalar tail (n % 4 elements; empty for the bench shape)
    {
        long long base = nvec << 2;
        long long rem  = ntot - base;
        if (tid0 < rem) process_elem(pred[base + tid0], target[base + tid0], cnt, fs);
    }

    // wave (64-lane) down-reduction
#pragma unroll
    for (int k = 0; k < NBINS; ++k) {
        unsigned int c = cnt[k];
        float        s = fs[k];
#pragma unroll
        for (int off = 32; off > 0; off >>= 1) {
            c += __shfl_down(c, off, 64);
            s += __shfl_down(s, off, 64);
        }
        cnt[k] = c;
        fs[k]  = s;
    }

    __shared__ unsigned int scnt[NW][NBINS];
    __shared__ float        ssum[NW][NBINS];
    int lane = threadIdx.x & 63;
    int wid  = threadIdx.x >> 6;
    if (lane == 0) {
#pragma unroll
        for (int k = 0; k < NBINS; ++k) {
            scnt[wid][k] = cnt[k];
            ssum[wid][k] = fs[k];
        }
    }
    __syncthreads();
    if (threadIdx.x == 0) {
        if (direct) {
            double loss = 0.0;
#pragma unroll
            for (int k = 0; k < NBINS; ++k) {
                unsigned int c = 0;
                double       s = 0.0;
#pragma unroll
                for (int w = 0; w < NW; ++w) { c += scnt[w][k]; s += (double)ssum[w][k]; }
                loss += s / (double)(c > 0u ? c : 1u);
            }
            out[0] = (float)(0.075 * loss);   // GHM/10; `total` cancels
        } else {
#pragma unroll
            for (int k = 0; k < NBINS; ++k) {
                unsigned int c = 0;
                float        s = 0.0f;
#pragma unroll
                for (int w = 0; w < NW; ++w) { c += scnt[w][k]; s += ssum[w][k]; }
                ws_cnt[(long long)blockIdx.x * NBINS + k] = c;
                ws_sum[(long long)blockIdx.x * NBINS + k] = s;
            }
        }
    }
}

// Deterministic finalize: 1 block reduces per-block partials, computes loss.
__global__ __launch_bounds__(256) void ghmc_final(
    const unsigned int* __restrict__ ws_cnt, const float* __restrict__ ws_sum,
    int nblocks, float* __restrict__ out) {
    unsigned long long c[NBINS] = {};
    double             s[NBINS] = {};
    for (int b = threadIdx.x; b < nblocks; b += 256) {
#pragma unroll
        for (int k = 0; k < NBINS; ++k) {
            c[k] += ws_cnt[b * NBINS + k];
            s[k] += (double)ws_sum[b * NBINS + k];
        }
    }
#pragma unroll
    for (int k = 0; k < NBINS; ++k) {
        unsigned long long cc = c[k];
        double             ss = s[k];
#pragma unroll
        for (int off = 32; off > 0; off >>= 1) {
            cc += __shfl_down(cc, off, 64);
            ss += __shfl_down(ss, off, 64);
        }
        c[k] = cc;
        s[k] = ss;
    }
    __shared__ unsigned long long sc[4][NBINS];
    __shared__ double             sd[4][NBINS];
    int lane = threadIdx.x & 63;
    int wid  = threadIdx.x >> 6;
    if (lane == 0) {
#pragma unroll
        for (int k = 0; k < NBINS; ++k) { sc[wid][k] = c[k]; sd[wid][k] = s[k]; }
    }
    __syncthreads();
    if (threadIdx.x == 0) {
        double loss = 0.0;
#pragma unroll
        for (int k = 0; k < NBINS; ++k) {
            unsigned long long cc = 0;
            double             ss = 0.0;
#pragma unroll
            for (int w = 0; w < 4; ++w) { cc += sc[w][k]; ss += sd[w][k]; }
            loss += ss / (double)(cc > 0 ? cc : 1ull);
        }
        out[0] = (float)(0.075 * loss);   // GHM/10; `total` cancels
    }
}

extern "C" void kernel_launch(void* const* d_in, const int* in_sizes, int n_in,
                              void* d_out, int out_size, void* d_ws, size_t ws_size,
                              hipStream_t stream) {
    const float* pred   = (const float*)d_in[0];
    const float* target = (const float*)d_in[1];
    float*       out    = (float*)d_out;
    long long n    = (long long)in_sizes[0];
    long long nvec = n >> 2;

    // per-block partials: 10 uint + 10 float = 80 B
    const size_t per_block = NBINS * (sizeof(unsigned int) + sizeof(float));
    long long g = (nvec + BLOCK - 1) / BLOCK;
    if (g > 2048) g = 2048;                           // grid-stride the rest
    long long g_ws = (long long)(ws_size / per_block);
    if (g > g_ws) g = g_ws;

    if (g < 1) {
        // ws-less fallback: one block does everything (slow but correct)
        ghmc_main<<<1, BLOCK, 0, stream>>>(pred, target, nullptr, nullptr,
                                           nvec, n, 1, out);
        return;
    }

    unsigned int* ws_cnt = (unsigned int*)d_ws;
    float*        ws_sum = (float*)((char*)d_ws + (size_t)g * NBINS * sizeof(unsigned int));

    ghmc_main<<<(int)g, BLOCK, 0, stream>>>(pred, target, ws_cnt, ws_sum,
                                            nvec, n, 0, out);
    ghmc_final<<<1, 256, 0, stream>>>(ws_cnt, ws_sum, (int)g, out);
}